// Round 2
// baseline (119.688 us; speedup 1.0000x reference)
//
#include <hip/hip_runtime.h>

#define CHUNK 512
#define NBINS 32
#define NCLS  10
#define MPAD  12   // masks padded to 12 floats/voxel -> 48B stride, float4-aligned

__global__ __launch_bounds__(256) void dvh_main(
    const float* __restrict__ pred, const float* __restrict__ targ,
    const float* __restrict__ mask, float* __restrict__ gD, float* __restrict__ gN,
    int chunksTotal, int chunksPerN)
{
    __shared__ float4 vox[CHUNK];          // Ep, Et, Et-Ep, pad   (8 KB)
    __shared__ float  ml[CHUNK * MPAD];    // padded masks         (24 KB)

    const int tid = threadIdx.x;
    const int g   = tid >> 5;    // voxel group 0..7
    const int bin = tid & 31;
    const float K = __expf((float)bin);    // e^bin

    float acc[NCLS];
    #pragma unroll
    for (int c = 0; c < NCLS; ++c) acc[c] = 0.f;
    float a0 = 0.f, a1 = 0.f;              // mask sums per n (exact, integer-valued)

    for (int chunk = blockIdx.x; chunk < chunksTotal; chunk += gridDim.x) {
        const float n0f = (chunk < chunksPerN) ? 1.f : 0.f;
        const float n1f = 1.f - n0f;
        const size_t vbase = (size_t)chunk * CHUNK;

        // ---- stage doses: compute exp once per voxel ----
        {
            const float2* p2 = (const float2*)(pred + vbase);
            const float2* t2 = (const float2*)(targ + vbase);
            float2 p = p2[tid];
            float2 t = t2[tid];
            float ep0 = __expf(-32.f * p.x), et0 = __expf(-32.f * t.x);
            float ep1 = __expf(-32.f * p.y), et1 = __expf(-32.f * t.y);
            vox[2 * tid + 0] = make_float4(ep0, et0, et0 - ep0, 0.f);
            vox[2 * tid + 1] = make_float4(ep1, et1, et1 - ep1, 0.f);
        }
        // ---- stage masks (coalesced float2, repack to 12-float stride) ----
        {
            const float2* m2 = (const float2*)(mask + vbase * NCLS);
            #pragma unroll
            for (int k = 0; k < (CHUNK * NCLS) / (2 * 256); ++k) {  // 10 iters
                int idx = k * 256 + tid;
                float2 mv = m2[idx];
                int f  = idx * 2;
                int vl = f / 10;
                int c  = f - vl * 10;      // even, pair never splits a voxel
                ml[vl * MPAD + c]     = mv.x;
                ml[vl * MPAD + c + 1] = mv.y;
            }
        }
        __syncthreads();

        // ---- compute: each thread = (voxel-group g, bin) ----
        #pragma unroll 4
        for (int v = g; v < CHUNK; v += 8) {
            float4 vd = vox[v];
            float ap = fmaf(vd.x, K, 1.f);
            float at = fmaf(vd.y, K, 1.f);
            float r  = __builtin_amdgcn_rcpf(ap * at);
            float sd = vd.z * K * r;       // sig_p - sig_t for this (voxel,bin)
            const float4* m4 = (const float4*)(ml + v * MPAD);
            float4 m0 = m4[0], m1 = m4[1], m2v = m4[2];
            acc[0] = fmaf(sd, m0.x, acc[0]);
            acc[1] = fmaf(sd, m0.y, acc[1]);
            acc[2] = fmaf(sd, m0.z, acc[2]);
            acc[3] = fmaf(sd, m0.w, acc[3]);
            acc[4] = fmaf(sd, m1.x, acc[4]);
            acc[5] = fmaf(sd, m1.y, acc[5]);
            acc[6] = fmaf(sd, m1.z, acc[6]);
            acc[7] = fmaf(sd, m1.w, acc[7]);
            acc[8] = fmaf(sd, m2v.x, acc[8]);
            acc[9] = fmaf(sd, m2v.y, acc[9]);
            if (bin < NCLS) {              // lanes 0..9 of each group: voxel count
                float mv = ml[v * MPAD + bin];
                a0 = fmaf(n0f, mv, a0);
                a1 = fmaf(n1f, mv, a1);
            }
        }
        __syncthreads();
    }

    // ---- block reduction ----
    #pragma unroll
    for (int c = 0; c < NCLS; ++c) acc[c] += __shfl_xor(acc[c], 32, 64);
    a0 += __shfl_xor(a0, 32, 64);
    a1 += __shfl_xor(a1, 32, 64);
    __syncthreads();

    float* red  = (float*)vox;             // 4*32*10 = 1280 floats (fits 8 KB)
    float* redN = ((float*)vox) + 1280;    // 4*10*2  = 80 floats
    const int w = tid >> 6;                // wave id 0..3
    if ((tid & 32) == 0) {
        #pragma unroll
        for (int c = 0; c < NCLS; ++c) red[(w * 32 + bin) * NCLS + c] = acc[c];
        if (bin < NCLS) {
            redN[(w * NCLS + bin) * 2 + 0] = a0;
            redN[(w * NCLS + bin) * 2 + 1] = a1;
        }
    }
    __syncthreads();

    // 320 gD entries reduced by 256 threads: grid-stride
    for (int i = tid; i < NBINS * NCLS; i += 256) {
        float s = red[i] + red[320 + i] + red[640 + i] + red[960 + i];
        atomicAdd(&gD[i], s);
    }
    // 20 gN entries: threads 0..19
    if (tid < 2 * NCLS) {
        int c = tid >> 1;
        int n = tid & 1;
        float s = redN[(0 * NCLS + c) * 2 + n] + redN[(1 * NCLS + c) * 2 + n]
                + redN[(2 * NCLS + c) * 2 + n] + redN[(3 * NCLS + c) * 2 + n];
        atomicAdd(&gN[n * NCLS + c], s);
    }
}

__global__ __launch_bounds__(512) void dvh_final(
    const float* __restrict__ gD, const float* __restrict__ gN, float* __restrict__ out)
{
    __shared__ float red[512];
    int t = threadIdx.x;
    float v = 0.f;
    if (t < NBINS * NCLS) {
        int c = t % NCLS;
        float nv0 = gN[c] + 1.f;
        float nv1 = gN[NCLS + c] + 1.f;
        float w = 1.f / (nv0 * nv0) + 1.f / (nv1 * nv1);
        float d = gD[t];
        v = d * d * w;
    }
    red[t] = v;
    __syncthreads();
    for (int s = 256; s > 0; s >>= 1) {
        if (t < s) red[t] += red[t + s];
        __syncthreads();
    }
    if (t == 0) out[0] = red[0] * (1.f / 1280.f);
}

extern "C" void kernel_launch(void* const* d_in, const int* in_sizes, int n_in,
                              void* d_out, int out_size, void* d_ws, size_t ws_size,
                              hipStream_t stream) {
    const float* pred = (const float*)d_in[0];
    const float* targ = (const float*)d_in[1];
    const float* mask = (const float*)d_in[2];
    float* gD = (float*)d_ws;                       // 320 floats: Delta[bin][c]
    float* gN = (float*)((char*)d_ws + 2048);       // 20 floats: sum-mask[n][c]

    hipMemsetAsync(d_ws, 0, 4096, stream);

    int totalVox   = in_sizes[0];           // N*V = 4194304
    int chunksTotal = totalVox / CHUNK;     // 8192
    int chunksPerN  = chunksTotal / 2;      // 4096

    dvh_main<<<1024, 256, 0, stream>>>(pred, targ, mask, gD, gN, chunksTotal, chunksPerN);
    dvh_final<<<1, 512, 0, stream>>>(gD, gN, (float*)d_out);
}

// Round 3
// 82.670 us; speedup vs baseline: 1.4478x; 1.4478x over previous
//
#include <hip/hip_runtime.h>

#define CHUNK 512
#define NBINS 32
#define NCLS  10
#define MPAD  12   // masks padded to 12 floats/voxel -> 48B stride, b128-aligned

__global__ __launch_bounds__(256) void dvh_main(
    const float* __restrict__ pred, const float* __restrict__ targ,
    const float* __restrict__ mask, float* __restrict__ gD, float* __restrict__ gN,
    int chunksTotal, int chunksPerN)
{
    __shared__ float4 vox[CHUNK];          // Ep, Et, Et-Ep, pad   (8 KB)
    __shared__ float  ml[CHUNK * MPAD];    // padded masks         (24 KB)

    const int tid = threadIdx.x;
    const int bg  = tid & 7;               // bin-group: bins 4*bg .. 4*bg+3
    const int vg  = tid >> 3;              // voxel-group 0..31

    const float Kb = __expf(4.f * (float)bg);
    float K[4];
    K[0] = Kb;
    K[1] = Kb * 2.71828182845904523536f;
    K[2] = Kb * 7.38905609893065022723f;
    K[3] = Kb * 20.0855369231876677409f;

    // second count class for bg<2 (classes 8,9); others disabled via sel=0
    const int   bgB  = (bg < 2) ? (bg + 8) : bg;
    const float selB = (bg < 2) ? 1.f : 0.f;

    float acc[4][NCLS];
    #pragma unroll
    for (int j = 0; j < 4; ++j)
        #pragma unroll
        for (int c = 0; c < NCLS; ++c) acc[j][c] = 0.f;
    float cnt[4] = {0.f, 0.f, 0.f, 0.f};   // [cA|n0, cA|n1, cB|n0, cB|n1]

    for (int chunk = blockIdx.x; chunk < chunksTotal; chunk += gridDim.x) {
        const float n0f = (chunk < chunksPerN) ? 1.f : 0.f;
        const float n1f = 1.f - n0f;
        const float n0s = n0f * selB, n1s = n1f * selB;
        const size_t vbase = (size_t)chunk * CHUNK;

        // ---- stage doses: exp once per voxel ----
        {
            const float2* p2 = (const float2*)(pred + vbase);
            const float2* t2 = (const float2*)(targ + vbase);
            float2 p = p2[tid];
            float2 t = t2[tid];
            float ep0 = __expf(-32.f * p.x), et0 = __expf(-32.f * t.x);
            float ep1 = __expf(-32.f * p.y), et1 = __expf(-32.f * t.y);
            vox[2*tid+0] = make_float4(ep0, et0, et0 - ep0, 0.f);
            vox[2*tid+1] = make_float4(ep1, et1, et1 - ep1, 0.f);
        }
        // ---- stage masks (coalesced float2, repack to 12-float stride) ----
        {
            const float2* m2 = (const float2*)(mask + vbase * NCLS);
            #pragma unroll
            for (int k = 0; k < (CHUNK * NCLS) / (2 * 256); ++k) {  // 10 iters
                int idx = k * 256 + tid;
                float2 mv = m2[idx];
                int f  = idx * 2;
                int vl = f / 10;
                int c  = f - vl * 10;      // even: pair never splits a voxel
                *(float2*)(&ml[vl * MPAD + c]) = mv;
            }
        }
        __syncthreads();

        // ---- compute: thread = (voxel-group vg, bin-group bg), 16 iters ----
        #pragma unroll 2
        for (int v = vg; v < CHUNK; v += 32) {
            float4 vd = vox[v];
            const float4* m4 = (const float4*)(ml + v * MPAD);
            float4 m0 = m4[0], m1 = m4[1], m2v = m4[2];
            float mcA = ml[v * MPAD + bg];
            float mcB = ml[v * MPAD + bgB];
            #pragma unroll
            for (int j = 0; j < 4; ++j) {
                float ap = fmaf(vd.x, K[j], 1.f);
                float at = fmaf(vd.y, K[j], 1.f);
                float r  = __builtin_amdgcn_rcpf(ap * at);
                float sd = vd.z * K[j] * r;   // sig_p - sig_t
                acc[j][0] = fmaf(sd, m0.x,  acc[j][0]);
                acc[j][1] = fmaf(sd, m0.y,  acc[j][1]);
                acc[j][2] = fmaf(sd, m0.z,  acc[j][2]);
                acc[j][3] = fmaf(sd, m0.w,  acc[j][3]);
                acc[j][4] = fmaf(sd, m1.x,  acc[j][4]);
                acc[j][5] = fmaf(sd, m1.y,  acc[j][5]);
                acc[j][6] = fmaf(sd, m1.z,  acc[j][6]);
                acc[j][7] = fmaf(sd, m1.w,  acc[j][7]);
                acc[j][8] = fmaf(sd, m2v.x, acc[j][8]);
                acc[j][9] = fmaf(sd, m2v.y, acc[j][9]);
            }
            cnt[0] = fmaf(n0f, mcA, cnt[0]);
            cnt[1] = fmaf(n1f, mcA, cnt[1]);
            cnt[2] = fmaf(n0s, mcB, cnt[2]);
            cnt[3] = fmaf(n1s, mcB, cnt[3]);
        }
        __syncthreads();
    }

    // ---- reduce across the 8 voxel-groups within each wave (lanes ^8,^16,^32) ----
    #pragma unroll
    for (int j = 0; j < 4; ++j)
        #pragma unroll
        for (int c = 0; c < NCLS; ++c) {
            float v = acc[j][c];
            v += __shfl_xor(v, 8, 64);
            v += __shfl_xor(v, 16, 64);
            v += __shfl_xor(v, 32, 64);
            acc[j][c] = v;
        }
    #pragma unroll
    for (int s = 0; s < 4; ++s) {
        float v = cnt[s];
        v += __shfl_xor(v, 8, 64);
        v += __shfl_xor(v, 16, 64);
        v += __shfl_xor(v, 32, 64);
        cnt[s] = v;
    }
    __syncthreads();

    float* red  = (float*)vox;             // 4 waves * 8 bg * 40 = 1280 floats (5 KB)
    float* redN = ml;                      // 4 waves * 8 bg * 4  = 128 floats
    const int w = tid >> 6;
    if ((tid & 63) < 8) {                  // lane = bg, vg-reduced values
        #pragma unroll
        for (int j = 0; j < 4; ++j)
            #pragma unroll
            for (int c = 0; c < NCLS; ++c)
                red[((w * 8 + bg) * 4 + j) * NCLS + c] = acc[j][c];
        #pragma unroll
        for (int s = 0; s < 4; ++s) redN[(w * 8 + bg) * 4 + s] = cnt[s];
    }
    __syncthreads();

    for (int i = tid; i < NBINS * NCLS; i += 256) {
        int b = i / NCLS, c = i - b * NCLS;
        int bgi = b >> 2, j = b & 3;
        float s = 0.f;
        #pragma unroll
        for (int ww = 0; ww < 4; ++ww)
            s += red[((ww * 8 + bgi) * 4 + j) * NCLS + c];
        atomicAdd(&gD[i], s);
    }
    if (tid < 2 * NCLS) {
        int c = tid >> 1, n = tid & 1;
        int bgi  = (c < 8) ? c : (c - 8);
        int slot = ((c < 8) ? 0 : 2) + n;
        float s = 0.f;
        #pragma unroll
        for (int ww = 0; ww < 4; ++ww)
            s += redN[(ww * 8 + bgi) * 4 + slot];
        atomicAdd(&gN[n * NCLS + c], s);
    }
}

__global__ __launch_bounds__(512) void dvh_final(
    const float* __restrict__ gD, const float* __restrict__ gN, float* __restrict__ out)
{
    __shared__ float red[512];
    int t = threadIdx.x;
    float v = 0.f;
    if (t < NBINS * NCLS) {
        int c = t % NCLS;
        float nv0 = gN[c] + 1.f;
        float nv1 = gN[NCLS + c] + 1.f;
        float w = 1.f / (nv0 * nv0) + 1.f / (nv1 * nv1);
        float d = gD[t];
        v = d * d * w;
    }
    red[t] = v;
    __syncthreads();
    for (int s = 256; s > 0; s >>= 1) {
        if (t < s) red[t] += red[t + s];
        __syncthreads();
    }
    if (t == 0) out[0] = red[0] * (1.f / 1280.f);
}

extern "C" void kernel_launch(void* const* d_in, const int* in_sizes, int n_in,
                              void* d_out, int out_size, void* d_ws, size_t ws_size,
                              hipStream_t stream) {
    const float* pred = (const float*)d_in[0];
    const float* targ = (const float*)d_in[1];
    const float* mask = (const float*)d_in[2];
    float* gD = (float*)d_ws;                       // 320 floats: Delta[bin][c]
    float* gN = (float*)((char*)d_ws + 2048);       // 20 floats: sum-mask[n][c]

    hipMemsetAsync(d_ws, 0, 4096, stream);

    int totalVox    = in_sizes[0];           // N*V = 4194304
    int chunksTotal = totalVox / CHUNK;      // 8192
    int chunksPerN  = chunksTotal / 2;       // 4096

    dvh_main<<<1024, 256, 0, stream>>>(pred, targ, mask, gD, gN, chunksTotal, chunksPerN);
    dvh_final<<<1, 512, 0, stream>>>(gD, gN, (float*)d_out);
}